// Round 9
// baseline (21.410 us; speedup 1.0000x reference)
//
#include <hip/hip_runtime.h>
#include <math.h>

// Problem constants (from reference setup_inputs)
#define B 8
#define S 512
#define G 16
#define DA 1024
#define DM 256
#define WIN 12
#define NCH 32                    // s-chunks per batch for partial max/sum
#define RPC (S / NCH)             // 16 rows per chunk
#define DTOT (DA + DM)            // 1280 pooled dims
#define NW 8                      // waves per block (512 threads)
#define RPW (RPC / NW)            // 2 rows per wave in the sweep
#define NWIN (B * (G - 1))        // 120 window blocks (placed first)
#define NBLK1 (NWIN + NCH * B)    // 376 blocks in K1

__inline__ __device__ float4 fmax4(float4 a, float4 b) {
    return make_float4(fmaxf(a.x, b.x), fmaxf(a.y, b.y),
                       fmaxf(a.z, b.z), fmaxf(a.w, b.w));
}
__inline__ __device__ float4 add4(float4 a, float4 b) {
    return make_float4(a.x + b.x, a.y + b.y, a.z + b.z, a.w + b.w);
}
__inline__ __device__ float dot4(float4 a, float4 b) {
    return a.x * b.x + a.y * b.y + a.z * b.z + a.w * b.w;
}

// 8-wave (512-thread) batched block reduce: 4 sums in one LDS round.
__inline__ __device__ float4 blockReduceSum4_8(float4 v, float4* sh) {
    int lane = threadIdx.x & 63, w = threadIdx.x >> 6;
#pragma unroll
    for (int o = 32; o > 0; o >>= 1) {
        v.x += __shfl_xor(v.x, o, 64);
        v.y += __shfl_xor(v.y, o, 64);
        v.z += __shfl_xor(v.z, o, 64);
        v.w += __shfl_xor(v.w, o, 64);
    }
    __syncthreads();
    if (lane == 0) sh[w] = v;
    __syncthreads();
    float4 r = sh[0];
#pragma unroll
    for (int ww = 1; ww < 8; ++ww) {
        r.x += sh[ww].x; r.y += sh[ww].y; r.z += sh[ww].z; r.w += sh[ww].w;
    }
    return r;
}

// K1: 376 blocks x 512 threads.
//  bid <  NWIN: window logit g>=1 (independent of sweep) -> writes out[b,g]
//  bid >= NWIN: sweep chunk -> pmax/psum partials (two-pass 40 KB LDS merge)
__global__ __launch_bounds__(512) void k_main(
    const float* __restrict__ att, const float* __restrict__ mod,
    const float* __restrict__ Wa, const float* __restrict__ Wm,
    const float* __restrict__ ba, const float* __restrict__ bm,
    const int* __restrict__ gidx, const int* __restrict__ mask,
    float* __restrict__ pmax, float* __restrict__ psum,
    float* __restrict__ out)
{
    __shared__ float part[NW][DTOT];   // 40 KB, shared by both paths
    __shared__ float4 s4[NW];
    const int bid = blockIdx.x;
    const int t = threadIdx.x, lane = t & 63, w = t >> 6;

    const float4* att4 = (const float4*)att;
    const float4* mod4 = (const float4*)mod;

    if (bid >= NWIN) {
        // ---------------- sweep chunk ----------------
        const int sid = bid - NWIN;
        const int b = sid >> 5, ch = sid & (NCH - 1);

        float4 amax[4], asum[4];
#pragma unroll
        for (int k = 0; k < 4; ++k) {
            amax[k] = make_float4(-INFINITY, -INFINITY, -INFINITY, -INFINITY);
            asum[k] = make_float4(0.f, 0.f, 0.f, 0.f);
        }
        float4 mmax = make_float4(-INFINITY, -INFINITY, -INFINITY, -INFINITY);
        float4 msum = make_float4(0.f, 0.f, 0.f, 0.f);

        const int row0 = b * S + ch * RPC + w * RPW;
#pragma unroll
        for (int r = 0; r < RPW; ++r) {
            const float4* arow = att4 + (size_t)(row0 + r) * (DA / 4);
#pragma unroll
            for (int k = 0; k < 4; ++k) {
                float4 v = arow[lane + 64 * k];
                amax[k] = fmax4(amax[k], v);
                asum[k] = add4(asum[k], v);
            }
            float4 vm = mod4[(size_t)(row0 + r) * (DM / 4) + lane];
            mmax = fmax4(mmax, vm);
            msum = add4(msum, vm);
        }

        const size_t base = ((size_t)b * NCH + ch) * DTOT;
        float4* pr = (float4*)&part[w][0];

        // Pass 1: maxes.
#pragma unroll
        for (int k = 0; k < 4; ++k) pr[lane + 64 * k] = amax[k];
        ((float4*)&part[w][DA])[lane] = mmax;
        __syncthreads();
        for (int d = t; d < DTOT; d += 512) {
            float mx = part[0][d];
#pragma unroll
            for (int ww = 1; ww < NW; ++ww) mx = fmaxf(mx, part[ww][d]);
            pmax[base + d] = mx;
        }
        __syncthreads();

        // Pass 2: sums.
#pragma unroll
        for (int k = 0; k < 4; ++k) pr[lane + 64 * k] = asum[k];
        ((float4*)&part[w][DA])[lane] = msum;
        __syncthreads();
        for (int d = t; d < DTOT; d += 512) {
            float sm = part[0][d];
#pragma unroll
            for (int ww = 1; ww < NW; ++ww) sm += part[ww][d];
            psum[base + d] = sm;
        }
    } else {
        // ---------------- window logit g>=1 ----------------
        const int b = bid / (G - 1), g = 1 + bid % (G - 1);
        const int gi = gidx[b * G + g];

        // Center-row gather dot: att[gi]·W0a + mod[gi]·W0m.
        float cd = 0.f;
        if (t < 256)
            cd = dot4(att4[(size_t)(b * S + gi) * (DA / 4) + t],
                      ((const float4*)Wa)[t]);
        else if (t < 256 + DM / 4)
            cd = dot4(mod4[(size_t)(b * S + gi) * (DM / 4) + (t - 256)],
                      ((const float4*)Wm)[t - 256]);

        int lo = gi - WIN; if (lo < 0) lo = 0;
        int hi = gi + WIN; if (hi > S - 1) hi = S - 1;

        // Per-d windowed masked max (clamped at 0 by the reference's x*wmf
        // form; window <= 25 < 512 rows always leaves zeros) and masked sum.
        float4 amax2[4], asum2[4];
#pragma unroll
        for (int k = 0; k < 4; ++k) {
            amax2[k] = make_float4(0.f, 0.f, 0.f, 0.f);
            asum2[k] = make_float4(0.f, 0.f, 0.f, 0.f);
        }
        float4 mmax2 = make_float4(0.f, 0.f, 0.f, 0.f);
        float4 msum2 = make_float4(0.f, 0.f, 0.f, 0.f);
        float cn = 0.f;

        for (int s = lo + w; s <= hi; s += NW) {
            if (mask[b * S + s] > 0) {
                const int row = b * S + s;
                const float4* arow = att4 + (size_t)row * (DA / 4);
#pragma unroll
                for (int k = 0; k < 4; ++k) {
                    float4 v = arow[lane + 64 * k];
                    amax2[k] = fmax4(amax2[k], v);
                    asum2[k] = add4(asum2[k], v);
                }
                float4 vm = mod4[(size_t)row * (DM / 4) + lane];
                mmax2 = fmax4(mmax2, vm);
                msum2 = add4(msum2, vm);
                if (lane == 0) cn += 1.f;
            }
        }

        float4* pr = (float4*)&part[w][0];

        // Pass 1: merge maxes, dot with max-slice weights.
#pragma unroll
        for (int k = 0; k < 4; ++k) pr[lane + 64 * k] = amax2[k];
        ((float4*)&part[w][DA])[lane] = mmax2;
        __syncthreads();
        float wdot1 = 0.f;
        for (int d = t; d < DTOT; d += 512) {
            float mx = part[0][d];
#pragma unroll
            for (int ww = 1; ww < 8; ++ww) mx = fmaxf(mx, part[ww][d]);
            float wgt = (d < DA) ? Wa[DA + d] : Wm[DM + (d - DA)];
            wdot1 += wgt * mx;
        }
        __syncthreads();

        // Pass 2: merge sums, dot with avg-slice weights.
#pragma unroll
        for (int k = 0; k < 4; ++k) pr[lane + 64 * k] = asum2[k];
        ((float4*)&part[w][DA])[lane] = msum2;
        __syncthreads();
        float wdot2 = 0.f;
        for (int d = t; d < DTOT; d += 512) {
            float sm = part[0][d];
#pragma unroll
            for (int ww = 1; ww < 8; ++ww) sm += part[ww][d];
            float wgt = (d < DA) ? Wa[2 * DA + d] : Wm[2 * DM + (d - DA)];
            wdot2 += wgt * sm;
        }

        float4 r = blockReduceSum4_8(make_float4(wdot1, wdot2, cd, cn), s4);
        if (t == 0)
            out[b * G + g] = r.z + r.x + r.y / r.w + ba[0] + bm[0];
    }
}

// K2: g==0 logits only, d-parallel with atomicAdd into out[b*G].
// grid (21, B): c<20 -> 64-d merge slice; c==20 -> center dot + bias.
__global__ __launch_bounds__(512) void k_g0(
    const float* __restrict__ att, const float* __restrict__ mod,
    const float* __restrict__ Wa, const float* __restrict__ Wm,
    const float* __restrict__ ba, const float* __restrict__ bm,
    const int* __restrict__ gidx, const int* __restrict__ mask,
    const float* __restrict__ pmax, const float* __restrict__ psum,
    float* __restrict__ out)
{
    __shared__ float pM[NW][64], pS[NW][64];
    __shared__ float4 s4[NW];
    const int c = blockIdx.x, b = blockIdx.y;
    const int t = threadIdx.x, lane = t & 63, w = t >> 6;

    // Global mask count (numerator of avg divides by it); S == 512 threads.
    float cmv = (float)mask[b * S + t];
    float cm = blockReduceSum4_8(make_float4(cmv, 0.f, 0.f, 0.f), s4).x;

    if (c < 20) {
        const int d = c * 64 + lane;
        // Wave w merges chunks {w, w+8, w+16, w+24}; coalesced 64-float reads.
        float mx = -INFINITY, sm = 0.f;
#pragma unroll
        for (int k = 0; k < NCH / NW; ++k) {
            const int ch = w + NW * k;
            const size_t o = ((size_t)b * NCH + ch) * DTOT + d;
            mx = fmaxf(mx, pmax[o]);
            sm += psum[o];
        }
        pM[w][lane] = mx;
        pS[w][lane] = sm;
        __syncthreads();

        float val = 0.f;
        if (t < 64) {
            float m2 = pM[0][t], s2 = pS[0][t];
#pragma unroll
            for (int ww = 1; ww < NW; ++ww) {
                m2 = fmaxf(m2, pM[ww][t]);
                s2 += pS[ww][t];
            }
            const int d2 = c * 64 + t;
            float w1 = (d2 < DA) ? Wa[DA + d2] : Wm[DM + (d2 - DA)];
            float w2 = (d2 < DA) ? Wa[2 * DA + d2] : Wm[2 * DM + (d2 - DA)];
            val = w1 * m2 + w2 * (s2 / cm);
        }
        if (w == 0) {
#pragma unroll
            for (int o = 32; o > 0; o >>= 1) val += __shfl_xor(val, o, 64);
            if (lane == 0) atomicAdd(&out[b * G], val);
        }
    } else {
        // Center-row gather dot + biases.
        const int gi = gidx[b * G];
        const float4* att4 = (const float4*)att;
        const float4* mod4 = (const float4*)mod;
        float cd = 0.f;
        if (t < 256)
            cd = dot4(att4[(size_t)(b * S + gi) * (DA / 4) + t],
                      ((const float4*)Wa)[t]);
        else if (t < 256 + DM / 4)
            cd = dot4(mod4[(size_t)(b * S + gi) * (DM / 4) + (t - 256)],
                      ((const float4*)Wm)[t - 256]);
        float4 r = blockReduceSum4_8(make_float4(cd, 0.f, 0.f, 0.f), s4);
        if (t == 0) atomicAdd(&out[b * G], r.x + ba[0] + bm[0]);
    }
}

extern "C" void kernel_launch(void* const* d_in, const int* in_sizes, int n_in,
                              void* d_out, int out_size, void* d_ws, size_t ws_size,
                              hipStream_t stream) {
    const float* att  = (const float*)d_in[0];
    const float* mod  = (const float*)d_in[1];
    const float* Wa   = (const float*)d_in[2];
    const float* ba   = (const float*)d_in[3];
    const float* Wm   = (const float*)d_in[4];
    const float* bm   = (const float*)d_in[5];
    // d_in[6] = q_enc (unused by reference)
    const int* gidx   = (const int*)d_in[7];
    const int* mask   = (const int*)d_in[8];
    // d_in[9] = q_mask (unused by reference)
    float* out = (float*)d_out;

    // Workspace layout (floats)
    float* ws   = (float*)d_ws;
    float* pmax = ws;                                   // B*NCH*DTOT
    float* psum = pmax + (size_t)B * NCH * DTOT;        // B*NCH*DTOT

    hipMemsetAsync(out, 0, (size_t)out_size * sizeof(float), stream);
    k_main<<<NBLK1, 512, 0, stream>>>(att, mod, Wa, Wm, ba, bm, gidx, mask,
                                      pmax, psum, out);
    k_g0<<<dim3(21, B), 512, 0, stream>>>(att, mod, Wa, Wm, ba, bm, gidx, mask,
                                          pmax, psum, out);
}